// Round 7
// baseline (642.027 us; speedup 1.0000x reference)
//
#include <hip/hip_runtime.h>

#define N_NODESC 50000
#define N_EDGESC 400000
#define N_GRAPHSC 128
#define IN_DIMC 768
#define HIDC 128
#define NCLSC 11
#define BN_EPSC 1e-5f
#define NB_AGG 8
#define NREP 64
#define SCAN_NB ((N_NODESC + 255) / 256)

typedef __bf16 bf16_t;
typedef __bf16 bf16x2 __attribute__((ext_vector_type(2)));
typedef __bf16 bf16x4 __attribute__((ext_vector_type(4)));
typedef __bf16 bf16x8 __attribute__((ext_vector_type(8)));
typedef float f32x4 __attribute__((ext_vector_type(4)));

typedef __attribute__((address_space(1))) void glb_void;
typedef __attribute__((address_space(3))) void lds_void;

__device__ __forceinline__ void cp16(const void* g, void* l) {
    // async global->LDS, 16B/lane; LDS dst = wave-uniform base + lane*16
    __builtin_amdgcn_global_load_lds((glb_void*)g, (lds_void*)l, 16, 0, 0);
}

__device__ __forceinline__ f32x4 mfma_16x16x32_bf16(bf16x8 a, bf16x8 b, f32x4 c) {
    return __builtin_amdgcn_mfma_f32_16x16x32_bf16(a, b, c, 0, 0, 0);
}

// ---------------- layer-1 GEMM (R5-proven config, REVERTED from R6):
// [Cl|Cr] = A[M,768]fp32 @ Wb^T, Wb[256,768]bf16. 128x256 tile, 256 threads,
// 391 blocks -> 2 blocks/CU. R6 lesson: staged-byte model holds only at
// >=2 blocks/CU (1 block/CU exposes the depth-1 convoy stall: 568 vs 557).
__global__ __launch_bounds__(256, 2) void gemm_l1_kernel(const float* __restrict__ Av,
                                                         const bf16_t* __restrict__ Wb,
                                                         bf16_t* __restrict__ Cl,
                                                         bf16_t* __restrict__ Cr,
                                                         int M)
{
    constexpr int KC  = IN_DIMC;          // 768
    constexpr int NK  = KC / 32;          // 24
    constexpr int ASZ = 16384;            // fp32 128x32
    constexpr int BSZ = 16384;            // bf16 256x32
    __shared__ __align__(16) unsigned char smem[2 * ASZ + 2 * BSZ];
    unsigned char* Asm = smem;
    unsigned char* Bsm = smem + 2 * ASZ;

    const int m0   = blockIdx.x * 128;
    const int t    = threadIdx.x;
    const int wid  = t >> 6;
    const int lane = t & 63;
    const int wm   = (wid >> 1) * 64;     // row half
    const int l16  = lane & 15;
    const int quad = lane >> 4;

    // ---- A loader: 4 chunks/wave, 16 KB/iter, XOR swizzle on global side ----
    const char* aSrc[4]; int aDst[4];
#pragma unroll
    for (int s = 0; s < 4; s++) {
        int L = (s * 4 + wid) * 64 + lane;            // 16B slot; LDS byte = L*16
        int r = L >> 3;                               // 0..127
        int c = (L & 7) ^ (r & 7);                    // 8 chunks per 128B row
        int row = m0 + r; if (row > M - 1) row = M - 1;  // clamp; never stored
        aSrc[s] = (const char*)Av + ((size_t)row * KC + (size_t)c * 4) * 4;
        aDst[s] = (s * 4 + wid) * 1024;
    }
    // ---- B loader: 4 chunks/wave, 16 KB/iter (all 256 Wb rows) ----
    const char* bSrc[4]; int bDst[4];
#pragma unroll
    for (int s = 0; s < 4; s++) {
        int L = (s * 4 + wid) * 64 + lane;
        int r = L >> 2;                               // 0..255
        int c = (L & 3) ^ ((r >> 1) & 3);
        bSrc[s] = (const char*)(Wb + (size_t)r * KC + c * 8);
        bDst[s] = (s * 4 + wid) * 1024;
    }

    // ---- fragment LDS byte offsets ----
    int aOff[4][2], bOff[8];
#pragma unroll
    for (int i = 0; i < 4; i++) {
        int ra = wm + i * 16 + l16;
        aOff[i][0] = ra * 128 + (((2 * quad)     ^ (ra & 7)) * 16);
        aOff[i][1] = ra * 128 + (((2 * quad + 1) ^ (ra & 7)) * 16);
    }
    const int wnb = (wid & 1) * 128;                  // output-col half
#pragma unroll
    for (int j = 0; j < 8; j++) {
        int rb = wnb + j * 16 + l16;                  // 0..255
        bOff[j] = rb * 64 + ((quad ^ ((rb >> 1) & 3)) * 16);
    }

    f32x4 acc[4][8] = {};

    // ---- depth-1 double buffer (R0-proven schedule) ----
#pragma unroll
    for (int s = 0; s < 4; s++) cp16(aSrc[s], Asm + aDst[s]);
#pragma unroll
    for (int s = 0; s < 4; s++) cp16(bSrc[s], Bsm + bDst[s]);

    for (int it = 0; it < NK; ++it) {
        if (it + 1 < NK) {
            const size_t ka = (size_t)(it + 1) * 128;
            const size_t kb = (size_t)(it + 1) * 64;
            const int nb = (it + 1) & 1;
#pragma unroll
            for (int s = 0; s < 4; s++) cp16(aSrc[s] + ka, Asm + nb * ASZ + aDst[s]);
#pragma unroll
            for (int s = 0; s < 4; s++) cp16(bSrc[s] + kb, Bsm + nb * BSZ + bDst[s]);
            asm volatile("s_waitcnt vmcnt(8)" ::: "memory");   // drain iter-it only
        } else {
            asm volatile("s_waitcnt vmcnt(0)" ::: "memory");
        }
        asm volatile("s_barrier" ::: "memory");

        const unsigned char* Ab = Asm + (it & 1) * ASZ;
        const unsigned char* Bb = Bsm + (it & 1) * BSZ;
        bf16x8 af[4], bfr[8];
#pragma unroll
        for (int i = 0; i < 4; i++) {
            float4 u0 = *(const float4*)(Ab + aOff[i][0]);
            float4 u1 = *(const float4*)(Ab + aOff[i][1]);
            af[i][0] = (bf16_t)u0.x; af[i][1] = (bf16_t)u0.y;
            af[i][2] = (bf16_t)u0.z; af[i][3] = (bf16_t)u0.w;
            af[i][4] = (bf16_t)u1.x; af[i][5] = (bf16_t)u1.y;
            af[i][6] = (bf16_t)u1.z; af[i][7] = (bf16_t)u1.w;
        }
#pragma unroll
        for (int j = 0; j < 8; j++)
            bfr[j] = *(const bf16x8*)(Bb + bOff[j]);
#pragma unroll
        for (int i = 0; i < 4; i++)
#pragma unroll
            for (int j = 0; j < 8; j++)
                acc[i][j] = mfma_16x16x32_bf16(af[i], bfr[j], acc[i][j]);

        asm volatile("s_barrier" ::: "memory");   // protect buf reused next iter
    }

    // C/D layout (m89-verified); wave col-half -> Cl or Cr directly
    bf16_t* C = (wid & 1) ? Cr : Cl;
#pragma unroll
    for (int i = 0; i < 4; i++) {
        int rowb = m0 + wm + i * 16 + quad * 4;
#pragma unroll
        for (int j = 0; j < 8; j++) {
            int colh = j * 16 + l16;
#pragma unroll
            for (int rr = 0; rr < 4; rr++) {
                int row = rowb + rr;
                if (row < M) C[(size_t)row * HIDC + colh] = (bf16_t)acc[i][j][rr];
            }
        }
    }
}

// ---------------- hidden-layer GEMM (K=128): R5-proven structure, REVERTED.
// A bf16 via cp16 depth-2 triple buffer; BN scale/shift computed in-kernel from
// stats replicas; BN+ReLU post-LDS-read. Pair-colocation grid (R1: FETCH halved).
__global__ __launch_bounds__(256) void gemm_hid_kernel(const bf16_t* __restrict__ Av,
                                                       const bf16_t* __restrict__ Wb,
                                                       const float* __restrict__ stats,
                                                       const float* __restrict__ g,
                                                       const float* __restrict__ be,
                                                       bf16_t* __restrict__ Cl,
                                                       bf16_t* __restrict__ Cr,
                                                       int M)
{
    constexpr int KC  = HIDC;             // 128
    constexpr int NK  = KC / 32;          // 4
    constexpr int ASZ = 8192;
    constexpr int BSZ = 8192;
    __shared__ __align__(16) unsigned char smem[3 * ASZ + 3 * BSZ + 1024];
    unsigned char* Asm = smem;
    unsigned char* Bsm = smem + 3 * ASZ;
    float* scS = (float*)(smem + 3 * ASZ + 3 * BSZ);

    const int bid  = blockIdx.x;
    const int p    = ((bid >> 4) << 3) + (bid & 7);
    const int half = (bid >> 3) & 1;
    if (p * 128 >= M) return;
    const int m0 = p * 128;

    const int t    = threadIdx.x;
    const int wid  = t >> 6;
    const int lane = t & 63;
    const int wm   = (wid >> 1) * 64;
    const int wn   = (wid & 1) * 64;
    const int l16  = lane & 15;
    const int quad = lane >> 4;

    const char* bSrc[2]; int bDst[2];
#pragma unroll
    for (int s = 0; s < 2; s++) {
        int L = (s * 4 + wid) * 64 + lane;
        int r = L >> 2;
        int c = (L & 3) ^ ((r >> 1) & 3);
        bSrc[s] = (const char*)(Wb + (size_t)(half * 128 + r) * KC + c * 8);
        bDst[s] = (s * 4 + wid) * 1024;
    }
    const char* aSrc[2]; int aDst[2];
#pragma unroll
    for (int s = 0; s < 2; s++) {
        int L = (s * 4 + wid) * 64 + lane;
        int r = L >> 2;
        int c = (L & 3) ^ ((r >> 1) & 3);
        int row = m0 + r; if (row > M - 1) row = M - 1;
        aSrc[s] = (const char*)Av + ((size_t)row * KC + (size_t)c * 8) * 2;
        aDst[s] = (s * 4 + wid) * 1024;
    }

    int aOff[4], bOff[4];
#pragma unroll
    for (int i = 0; i < 4; i++) {
        int ra = wm + i * 16 + l16;
        aOff[i] = ra * 64 + ((quad ^ ((ra >> 1) & 3)) * 16);
        int rb = wn + i * 16 + l16;
        bOff[i] = rb * 64 + ((quad ^ ((rb >> 1) & 3)) * 16);
    }

    // fused BN finalize -> scale/shift in LDS (drained before barrier)
    if (t < HIDC) {
        float sum = 0.f, sumsq = 0.f;
        for (int r = 0; r < NREP; r++) {
            sum   += stats[r * 256 + t];
            sumsq += stats[r * 256 + HIDC + t];
        }
        float invM = 1.0f / (float)M;
        float mean = sum * invM;
        float var  = sumsq * invM - mean * mean;
        float s = rsqrtf(var + BN_EPSC) * g[t];
        scS[t] = s;
        scS[HIDC + t] = be[t] - mean * s;
    }
    __syncthreads();

    f32x4 acc[4][4] = {};

#pragma unroll
    for (int s = 0; s < 2; s++) cp16(aSrc[s], Asm + aDst[s]);
#pragma unroll
    for (int s = 0; s < 2; s++) cp16(bSrc[s], Bsm + bDst[s]);
#pragma unroll
    for (int s = 0; s < 2; s++) cp16(aSrc[s] + 64, Asm + ASZ + aDst[s]);
#pragma unroll
    for (int s = 0; s < 2; s++) cp16(bSrc[s] + 64, Bsm + BSZ + bDst[s]);

    for (int it = 0; it < NK; ++it) {
        if (it + 2 < NK) {
            const size_t kb2 = (size_t)(it + 2) * 64;
            const int nb = (it + 2) % 3;
#pragma unroll
            for (int s = 0; s < 2; s++) cp16(aSrc[s] + kb2, Asm + nb * ASZ + aDst[s]);
#pragma unroll
            for (int s = 0; s < 2; s++) cp16(bSrc[s] + kb2, Bsm + nb * BSZ + bDst[s]);
            asm volatile("s_waitcnt vmcnt(8)" ::: "memory");
        } else if (it + 1 < NK) {
            asm volatile("s_waitcnt vmcnt(4)" ::: "memory");
        } else {
            asm volatile("s_waitcnt vmcnt(0)" ::: "memory");
        }
        asm volatile("s_barrier" ::: "memory");

        const unsigned char* Ab = Asm + (it % 3) * ASZ;
        const unsigned char* Bb = Bsm + (it % 3) * BSZ;
        bf16x8 af[4], bfr[4];
        float4 s0 = *(const float4*)&scS[it * 32 + quad * 8];
        float4 s1 = *(const float4*)&scS[it * 32 + quad * 8 + 4];
        float4 h0 = *(const float4*)&scS[HIDC + it * 32 + quad * 8];
        float4 h1 = *(const float4*)&scS[HIDC + it * 32 + quad * 8 + 4];
        float ss[8] = {s0.x, s0.y, s0.z, s0.w, s1.x, s1.y, s1.z, s1.w};
        float hh[8] = {h0.x, h0.y, h0.z, h0.w, h1.x, h1.y, h1.z, h1.w};
#pragma unroll
        for (int i = 0; i < 4; i++) {
            bf16x8 raw = *(const bf16x8*)(Ab + aOff[i]);
#pragma unroll
            for (int e = 0; e < 8; e++)
                af[i][e] = (bf16_t)fmaxf(fmaf((float)raw[e], ss[e], hh[e]), 0.0f);
        }
#pragma unroll
        for (int j = 0; j < 4; j++)
            bfr[j] = *(const bf16x8*)(Bb + bOff[j]);
#pragma unroll
        for (int i = 0; i < 4; i++)
#pragma unroll
            for (int j = 0; j < 4; j++)
                acc[i][j] = mfma_16x16x32_bf16(af[i], bfr[j], acc[i][j]);

        asm volatile("s_barrier" ::: "memory");
    }

    bf16_t* C = half ? Cr : Cl;
#pragma unroll
    for (int i = 0; i < 4; i++) {
        int rowb = m0 + wm + i * 16 + quad * 4;
#pragma unroll
        for (int j = 0; j < 4; j++) {
            int colh = wn + j * 16 + l16;
#pragma unroll
            for (int rr = 0; rr < 4; rr++) {
                int row = rowb + rr;
                if (row < M) C[(size_t)row * HIDC + colh] = (bf16_t)acc[i][j][rr];
            }
        }
    }
}

// ---------- fused init: weight converts + zero degi/stats ----------
__global__ void init_kernel(const float* __restrict__ W1l, const float* __restrict__ W1r,
                            const float* __restrict__ W2l, const float* __restrict__ W2r,
                            const float* __restrict__ W3l, const float* __restrict__ W3r,
                            bf16_t* __restrict__ Wb1, bf16_t* __restrict__ Wb2,
                            bf16_t* __restrict__ Wb3,
                            int* __restrict__ degi, float* __restrict__ stats)
{
    const int NW1 = 128 * IN_DIMC;
    const int NW2 = 128 * HIDC;
    const int NS  = 3 * NREP * 256;
    int j = blockIdx.x * blockDim.x + threadIdx.x;
    if (j < 2 * NW1) { Wb1[j] = (bf16_t)((j < NW1) ? W1l[j] : W1r[j - NW1]); return; }
    j -= 2 * NW1;
    if (j < 2 * NW2) { Wb2[j] = (bf16_t)((j < NW2) ? W2l[j] : W2r[j - NW2]); return; }
    j -= 2 * NW2;
    if (j < 2 * NW2) { Wb3[j] = (bf16_t)((j < NW2) ? W3l[j] : W3r[j - NW2]); return; }
    j -= 2 * NW2;
    if (j < NS) { stats[j] = 0.0f; return; }
    j -= NS;
    if (j < N_NODESC) degi[j] = 0;
}

// ---------- CSR build ----------
__global__ void degi_kernel(const int* __restrict__ ei, int* __restrict__ degi) {
    int e = blockIdx.x * blockDim.x + threadIdx.x;
    if (e < N_EDGESC) atomicAdd(&degi[ei[N_EDGESC + e]], 1);
}

__global__ __launch_bounds__(256) void scan1_kernel(const int* __restrict__ degi,
                                                    int* __restrict__ local,
                                                    int* __restrict__ partials)
{
    __shared__ int tmp[256];
    const int t = threadIdx.x;
    const int i = blockIdx.x * 256 + t;
    int v = (i < N_NODESC) ? degi[i] : 0;
    tmp[t] = v;
    __syncthreads();
    for (int off = 1; off < 256; off <<= 1) {
        int u = (t >= off) ? tmp[t - off] : 0;
        __syncthreads();
        tmp[t] += u;
        __syncthreads();
    }
    if (i < N_NODESC) local[i] = tmp[t] - v;
    if (t == 255) partials[blockIdx.x] = tmp[255];
}

// scan3 with the 196-partial scan folded in (replaces the scan2 dispatch)
__global__ __launch_bounds__(256) void scan3_kernel(const int* __restrict__ local,
                                                    const int* __restrict__ partials,
                                                    int* __restrict__ rowptr,
                                                    int* __restrict__ cursor)
{
    __shared__ int inc[256];
    __shared__ int orig[256];
    const int t = threadIdx.x;
    int v = (t < SCAN_NB) ? partials[t] : 0;
    inc[t] = v; orig[t] = v;
    __syncthreads();
    for (int off = 1; off < 256; off <<= 1) {
        int u = (t >= off) ? inc[t - off] : 0;
        __syncthreads();
        inc[t] += u;
        __syncthreads();
    }
    const int boff = inc[blockIdx.x] - orig[blockIdx.x];   // exclusive offset, broadcast
    const int i = blockIdx.x * 256 + t;
    if (i < N_NODESC) {
        int r = local[i] + boff;
        rowptr[i] = r;
        cursor[i] = r;
    }
    if (i == 0) rowptr[N_NODESC] = N_EDGESC;
}

__global__ void fill_kernel(const int* __restrict__ ei, int* __restrict__ cursor,
                            int* __restrict__ col) {
    int e = blockIdx.x * blockDim.x + threadIdx.x;
    if (e >= N_EDGESC) return;
    int d = ei[N_EDGESC + e];
    int pos = atomicAdd(&cursor[d], 1);
    col[pos] = ei[e];
}

// ---------- fused CSR-gather mean-agg + bias + Pr + BN partial sums ----------
// R7: widened gather -- 8 B/lane bf16x4, lane parity h=lane>>5 picks the edge;
// one load instruction covers TWO edge-rows (64 lanes x 8B = 512B). Halves the
// gather instruction count at identical bytes and round structure. Partials
// combined cross-parity via __shfl_xor(.,32). NO device-scope fences (R8).
__global__ __launch_bounds__(128) void agg_combine_kernel(const int* __restrict__ rowptr,
                                                          const int* __restrict__ col,
                                                          const bf16_t* __restrict__ Plb,
                                                          const bf16_t* __restrict__ Prb,
                                                          const float* __restrict__ bias,
                                                          bf16_t* __restrict__ Hb,
                                                          float* __restrict__ stats, int M)
{
    const int lane = threadIdx.x & 63;
    const int wv   = threadIdx.x >> 6;
    const int h    = lane >> 5;           // edge parity (0: even edges, 1: odd)
    const int cl   = lane & 31;
    const int c0   = cl * 4;              // 4 channels per lane
    float b[4];
#pragma unroll
    for (int k = 0; k < 4; k++) b[k] = bias[c0 + k];
    const int n0 = blockIdx.x * NB_AGG + wv * (NB_AGG / 2);

    int lo[4], hi[4], pos[4];
#pragma unroll
    for (int r = 0; r < 4; r++) {
        int n = n0 + r;
        lo[r] = (n < M) ? rowptr[n] : 0;
        hi[r] = (n < M) ? rowptr[n + 1] : 0;
        pos[r] = lo[r];
    }

    float a[4][4] = {};

    for (;;) {
        int cnt[4];
        bool any = false;
#pragma unroll
        for (int r = 0; r < 4; r++) {
            int c = hi[r] - pos[r];
            cnt[r] = (c > 8) ? 8 : c;
            if (cnt[r] > 0) any = true;
        }
        if (!any) break;

        bf16x4 v[4][4];
#pragma unroll
        for (int r = 0; r < 4; r++) {
            if (cnt[r] > 0) {                       // wave-uniform branch
#pragma unroll
                for (int j = 0; j < 4; j++) {
                    int ee = pos[r] + 2 * j + h;    // this lane's edge
                    if (ee > hi[r] - 1) ee = hi[r] - 1;
                    int idx = col[ee];              // 2-way broadcast load
                    v[r][j] = *(const bf16x4*)&Plb[(size_t)idx * HIDC + c0];
                }
            }
        }
#pragma unroll
        for (int r = 0; r < 4; r++) {
            if (cnt[r] > 0) {
#pragma unroll
                for (int j = 0; j < 4; j++)
                    if (2 * j + h < cnt[r]) {
#pragma unroll
                        for (int k = 0; k < 4; k++) a[r][k] += (float)v[r][j][k];
                    }
                pos[r] += cnt[r];
            }
        }
    }

    // cross-parity combine: each lane adds its partner's partial
#pragma unroll
    for (int r = 0; r < 4; r++)
#pragma unroll
        for (int k = 0; k < 4; k++)
            a[r][k] += __shfl_xor(a[r][k], 32, 64);

    if (h == 0) {
        float s[4] = {0.f, 0.f, 0.f, 0.f}, q[4] = {0.f, 0.f, 0.f, 0.f};
#pragma unroll
        for (int r = 0; r < 4; r++) {
            int n = n0 + r;
            if (n < M) {
                int d = hi[r] - lo[r];
                float inv = 1.0f / (float)(d > 0 ? d : 1);
                bf16x4 pr = *(const bf16x4*)&Prb[(size_t)n * HIDC + c0];
                bf16x4 hv;
                float pre;
#pragma unroll
                for (int k = 0; k < 4; k++) {
                    pre = fmaf(a[r][k], inv, b[k]) + (float)pr[k];
                    hv[k] = (bf16_t)pre;
                    s[k] += pre; q[k] += pre * pre;
                }
                *(bf16x4*)&Hb[(size_t)n * HIDC + c0] = hv;
            }
        }
        const int rep = (blockIdx.x * 2 + wv) & (NREP - 1);
#pragma unroll
        for (int k = 0; k < 4; k++) {
            atomicAdd(&stats[rep * 256 + c0 + k], s[k]);
            atomicAdd(&stats[rep * 256 + HIDC + c0 + k], q[k]);
        }
    }
}

// ---------- fused BN3-finalize + pool + linear head ----------
__global__ __launch_bounds__(128) void poolhead_kernel(const bf16_t* __restrict__ Hb,
                                                       const float* __restrict__ stats,
                                                       const float* __restrict__ g,
                                                       const float* __restrict__ be,
                                                       const int* __restrict__ batch,
                                                       const float* __restrict__ Wlin,
                                                       const float* __restrict__ blin,
                                                       float* __restrict__ out, int M)
{
    __shared__ float sp[HIDC];
    int gph = blockIdx.x;
    int c   = threadIdx.x;
    float sum = 0.f, sumsq = 0.f;
    for (int r = 0; r < NREP; r++) {
        sum   += stats[r * 256 + c];
        sumsq += stats[r * 256 + HIDC + c];
    }
    float invM = 1.0f / (float)M;
    float mean = sum * invM;
    float var  = sumsq * invM - mean * mean;
    float s = rsqrtf(var + BN_EPSC) * g[c];
    float h = be[c] - mean * s;

    int lo = 0, hi = M;
    while (lo < hi) { int m = (lo + hi) >> 1; if (batch[m] < gph) lo = m + 1; else hi = m; }
    int lo2 = lo, hi2 = M;
    while (lo2 < hi2) { int m = (lo2 + hi2) >> 1; if (batch[m] < gph + 1) lo2 = m + 1; else hi2 = m; }
    float mx = -INFINITY;
    for (int rr = lo; rr < lo2; rr++)
        mx = fmaxf(mx, fmaf((float)Hb[(size_t)rr * HIDC + c], s, h));
    sp[c] = mx;
    __syncthreads();
    if (c < NCLSC) {
        float acc = blin[c];
        for (int k = 0; k < HIDC; k++) acc += sp[k] * Wlin[c * HIDC + k];
        out[gph * NCLSC + c] = acc;
    }
}

extern "C" void kernel_launch(void* const* d_in, const int* in_sizes, int n_in,
                              void* d_out, int out_size, void* d_ws, size_t ws_size,
                              hipStream_t stream)
{
    const float* x     = (const float*)d_in[0];
    const int*   ei    = (const int*)d_in[1];
    const int*   batch = (const int*)d_in[2];
    const float* W1l = (const float*)d_in[3];
    const float* b1  = (const float*)d_in[4];
    const float* W1r = (const float*)d_in[5];
    const float* g1  = (const float*)d_in[6];
    const float* be1 = (const float*)d_in[7];
    const float* W2l = (const float*)d_in[8];
    const float* b2  = (const float*)d_in[9];
    const float* W2r = (const float*)d_in[10];
    const float* g2  = (const float*)d_in[11];
    const float* be2 = (const float*)d_in[12];
    const float* W3l = (const float*)d_in[13];
    const float* b3  = (const float*)d_in[14];
    const float* W3r = (const float*)d_in[15];
    const float* g3  = (const float*)d_in[16];
    const float* be3 = (const float*)d_in[17];
    const float* Wlin = (const float*)d_in[18];
    const float* blin = (const float*)d_in[19];

    const int M = N_NODESC;

    // workspace carve (16B aligned)
    char* w = (char*)d_ws;
    bf16_t* Plb  = (bf16_t*)w;  w += (size_t)M * HIDC * 2;
    bf16_t* Prb  = (bf16_t*)w;  w += (size_t)M * HIDC * 2;
    bf16_t* Hb   = (bf16_t*)w;  w += (size_t)M * HIDC * 2;
    bf16_t* Wb1  = (bf16_t*)w;  w += (size_t)256 * IN_DIMC * 2;
    bf16_t* Wb2  = (bf16_t*)w;  w += (size_t)256 * HIDC * 2;
    bf16_t* Wb3  = (bf16_t*)w;  w += (size_t)256 * HIDC * 2;
    int*   rowptr= (int*)w;     w += (size_t)(M + 16) * 4;
    int*   col   = (int*)w;     w += (size_t)N_EDGESC * 4;
    int*   cursor= (int*)w;     w += (size_t)M * 4;
    int*   degi  = (int*)w;     w += (size_t)M * 4;
    int*   slocal= (int*)w;     w += (size_t)M * 4;
    int*   spart = (int*)w;     w += 256 * 4;
    float* stats = (float*)w;   w += (size_t)3 * NREP * 256 * 4;   // zeroed in init

    float* stats1 = stats;
    float* stats2 = stats + NREP * 256;
    float* stats3 = stats + 2 * NREP * 256;

    const int nP128 = (M + 127) / 128;                  // 391
    const dim3 l1_grid(nP128);                          // fused 128x256 tile
    const dim3 hid_grid(((nP128 + 7) / 8) * 16);        // pair-colocation decode
    const int agg_blocks = (M + NB_AGG - 1) / NB_AGG;
    const int init_total = 2 * 128 * IN_DIMC + 4 * 128 * HIDC + 3 * NREP * 256 + M;

    // ---- init (weights + zeros, one dispatch) ----
    init_kernel<<<(init_total + 255) / 256, 256, 0, stream>>>(W1l, W1r, W2l, W2r, W3l, W3r,
                                                              Wb1, Wb2, Wb3, degi, stats);
    // ---- CSR build (4 dispatches) ----
    degi_kernel<<<(N_EDGESC + 255) / 256, 256, 0, stream>>>(ei, degi);
    scan1_kernel<<<SCAN_NB, 256, 0, stream>>>(degi, slocal, spart);
    scan3_kernel<<<SCAN_NB, 256, 0, stream>>>(slocal, spart, rowptr, cursor);
    fill_kernel<<<(N_EDGESC + 255) / 256, 256, 0, stream>>>(ei, cursor, col);

    // ---- layer 1 (K=768, fused 128x256 tile, R5 config) ----
    gemm_l1_kernel<<<l1_grid, 256, 0, stream>>>(x, Wb1, Plb, Prb, M);
    agg_combine_kernel<<<agg_blocks, 128, 0, stream>>>(rowptr, col, Plb, Prb, b1, Hb, stats1, M);

    // ---- layer 2 (K=128; BN1 finalize + BN1+ReLU fused into the GEMM) ----
    gemm_hid_kernel<<<hid_grid, 256, 0, stream>>>(Hb, Wb2, stats1, g1, be1, Plb, Prb, M);
    agg_combine_kernel<<<agg_blocks, 128, 0, stream>>>(rowptr, col, Plb, Prb, b2, Hb, stats2, M);

    // ---- layer 3 (K=128; BN2 finalize + BN2+ReLU fused) ----
    gemm_hid_kernel<<<hid_grid, 256, 0, stream>>>(Hb, Wb3, stats2, g2, be2, Plb, Prb, M);
    agg_combine_kernel<<<agg_blocks, 128, 0, stream>>>(rowptr, col, Plb, Prb, b3, Hb, stats3, M);

    // ---- BN3 finalize + pool + head (one dispatch) ----
    poolhead_kernel<<<N_GRAPHSC, 128, 0, stream>>>(Hb, stats3, g3, be3, batch, Wlin, blin,
                                                   (float*)d_out, M);
}

// Round 8
// 561.390 us; speedup vs baseline: 1.1436x; 1.1436x over previous
//
#include <hip/hip_runtime.h>

#define N_NODESC 50000
#define N_EDGESC 400000
#define N_GRAPHSC 128
#define IN_DIMC 768
#define HIDC 128
#define NCLSC 11
#define BN_EPSC 1e-5f
#define NB_AGG 8
#define NREP 64
#define SCAN_NB ((N_NODESC + 255) / 256)

typedef __bf16 bf16_t;
typedef __bf16 bf16x2 __attribute__((ext_vector_type(2)));
typedef __bf16 bf16x8 __attribute__((ext_vector_type(8)));
typedef float f32x4 __attribute__((ext_vector_type(4)));

typedef __attribute__((address_space(1))) void glb_void;
typedef __attribute__((address_space(3))) void lds_void;

__device__ __forceinline__ void cp16(const void* g, void* l) {
    // async global->LDS, 16B/lane; LDS dst = wave-uniform base + lane*16
    __builtin_amdgcn_global_load_lds((glb_void*)g, (lds_void*)l, 16, 0, 0);
}

__device__ __forceinline__ f32x4 mfma_16x16x32_bf16(bf16x8 a, bf16x8 b, f32x4 c) {
    return __builtin_amdgcn_mfma_f32_16x16x32_bf16(a, b, c, 0, 0, 0);
}

// ---------------- layer-1 GEMM (R5-proven config):
// [Cl|Cr] = A[M,768]fp32 @ Wb^T, Wb[256,768]bf16. 128x256 tile, 256 threads,
// 391 blocks -> 2 blocks/CU. R6 lesson: staged-byte model holds only at
// >=2 blocks/CU (1 block/CU exposes the depth-1 convoy stall).
__global__ __launch_bounds__(256, 2) void gemm_l1_kernel(const float* __restrict__ Av,
                                                         const bf16_t* __restrict__ Wb,
                                                         bf16_t* __restrict__ Cl,
                                                         bf16_t* __restrict__ Cr,
                                                         int M)
{
    constexpr int KC  = IN_DIMC;          // 768
    constexpr int NK  = KC / 32;          // 24
    constexpr int ASZ = 16384;            // fp32 128x32
    constexpr int BSZ = 16384;            // bf16 256x32
    __shared__ __align__(16) unsigned char smem[2 * ASZ + 2 * BSZ];
    unsigned char* Asm = smem;
    unsigned char* Bsm = smem + 2 * ASZ;

    const int m0   = blockIdx.x * 128;
    const int t    = threadIdx.x;
    const int wid  = t >> 6;
    const int lane = t & 63;
    const int wm   = (wid >> 1) * 64;     // row half
    const int l16  = lane & 15;
    const int quad = lane >> 4;

    // ---- A loader: 4 chunks/wave, 16 KB/iter, XOR swizzle on global side ----
    const char* aSrc[4]; int aDst[4];
#pragma unroll
    for (int s = 0; s < 4; s++) {
        int L = (s * 4 + wid) * 64 + lane;            // 16B slot; LDS byte = L*16
        int r = L >> 3;                               // 0..127
        int c = (L & 7) ^ (r & 7);                    // 8 chunks per 128B row
        int row = m0 + r; if (row > M - 1) row = M - 1;  // clamp; never stored
        aSrc[s] = (const char*)Av + ((size_t)row * KC + (size_t)c * 4) * 4;
        aDst[s] = (s * 4 + wid) * 1024;
    }
    // ---- B loader: 4 chunks/wave, 16 KB/iter (all 256 Wb rows) ----
    const char* bSrc[4]; int bDst[4];
#pragma unroll
    for (int s = 0; s < 4; s++) {
        int L = (s * 4 + wid) * 64 + lane;
        int r = L >> 2;                               // 0..255
        int c = (L & 3) ^ ((r >> 1) & 3);
        bSrc[s] = (const char*)(Wb + (size_t)r * KC + c * 8);
        bDst[s] = (s * 4 + wid) * 1024;
    }

    // ---- fragment LDS byte offsets ----
    int aOff[4][2], bOff[8];
#pragma unroll
    for (int i = 0; i < 4; i++) {
        int ra = wm + i * 16 + l16;
        aOff[i][0] = ra * 128 + (((2 * quad)     ^ (ra & 7)) * 16);
        aOff[i][1] = ra * 128 + (((2 * quad + 1) ^ (ra & 7)) * 16);
    }
    const int wnb = (wid & 1) * 128;                  // output-col half
#pragma unroll
    for (int j = 0; j < 8; j++) {
        int rb = wnb + j * 16 + l16;                  // 0..255
        bOff[j] = rb * 64 + ((quad ^ ((rb >> 1) & 3)) * 16);
    }

    f32x4 acc[4][8] = {};

    // ---- depth-1 double buffer (R0-proven schedule) ----
#pragma unroll
    for (int s = 0; s < 4; s++) cp16(aSrc[s], Asm + aDst[s]);
#pragma unroll
    for (int s = 0; s < 4; s++) cp16(bSrc[s], Bsm + bDst[s]);

    for (int it = 0; it < NK; ++it) {
        if (it + 1 < NK) {
            const size_t ka = (size_t)(it + 1) * 128;
            const size_t kb = (size_t)(it + 1) * 64;
            const int nb = (it + 1) & 1;
#pragma unroll
            for (int s = 0; s < 4; s++) cp16(aSrc[s] + ka, Asm + nb * ASZ + aDst[s]);
#pragma unroll
            for (int s = 0; s < 4; s++) cp16(bSrc[s] + kb, Bsm + nb * BSZ + bDst[s]);
            asm volatile("s_waitcnt vmcnt(8)" ::: "memory");   // drain iter-it only
        } else {
            asm volatile("s_waitcnt vmcnt(0)" ::: "memory");
        }
        asm volatile("s_barrier" ::: "memory");

        const unsigned char* Ab = Asm + (it & 1) * ASZ;
        const unsigned char* Bb = Bsm + (it & 1) * BSZ;
        bf16x8 af[4], bfr[8];
#pragma unroll
        for (int i = 0; i < 4; i++) {
            float4 u0 = *(const float4*)(Ab + aOff[i][0]);
            float4 u1 = *(const float4*)(Ab + aOff[i][1]);
            af[i][0] = (bf16_t)u0.x; af[i][1] = (bf16_t)u0.y;
            af[i][2] = (bf16_t)u0.z; af[i][3] = (bf16_t)u0.w;
            af[i][4] = (bf16_t)u1.x; af[i][5] = (bf16_t)u1.y;
            af[i][6] = (bf16_t)u1.z; af[i][7] = (bf16_t)u1.w;
        }
#pragma unroll
        for (int j = 0; j < 8; j++)
            bfr[j] = *(const bf16x8*)(Bb + bOff[j]);
#pragma unroll
        for (int i = 0; i < 4; i++)
#pragma unroll
            for (int j = 0; j < 8; j++)
                acc[i][j] = mfma_16x16x32_bf16(af[i], bfr[j], acc[i][j]);

        asm volatile("s_barrier" ::: "memory");   // protect buf reused next iter
    }

    // C/D layout (m89-verified); wave col-half -> Cl or Cr directly
    bf16_t* C = (wid & 1) ? Cr : Cl;
#pragma unroll
    for (int i = 0; i < 4; i++) {
        int rowb = m0 + wm + i * 16 + quad * 4;
#pragma unroll
        for (int j = 0; j < 8; j++) {
            int colh = j * 16 + l16;
#pragma unroll
            for (int rr = 0; rr < 4; rr++) {
                int row = rowb + rr;
                if (row < M) C[(size_t)row * HIDC + colh] = (bf16_t)acc[i][j][rr];
            }
        }
    }
}

// ---------------- hidden-layer GEMM (K=128): R8 single variable -- fused
// 128x256 tile (A staged ONCE per panel; staged bytes 50->37.5 MB/layer,
// blocks 784->391, 49 KB LDS -> 3 blocks/CU >= 2, satisfies R6 constraint).
// BN finalize in-kernel; BN+ReLU post-LDS-read. Depth-1, 6 cp16/thread/iter.
__global__ __launch_bounds__(256) void gemm_hid_kernel(const bf16_t* __restrict__ Av,
                                                       const bf16_t* __restrict__ Wb,
                                                       const float* __restrict__ stats,
                                                       const float* __restrict__ g,
                                                       const float* __restrict__ be,
                                                       bf16_t* __restrict__ Cl,
                                                       bf16_t* __restrict__ Cr,
                                                       int M)
{
    constexpr int KC  = HIDC;             // 128
    constexpr int NK  = KC / 32;          // 4
    constexpr int ASZ = 8192;             // bf16 128x32
    constexpr int BSZ = 16384;            // bf16 256x32
    __shared__ __align__(16) unsigned char smem[2 * ASZ + 2 * BSZ + 1024];
    unsigned char* Asm = smem;
    unsigned char* Bsm = smem + 2 * ASZ;
    float* scS = (float*)(smem + 2 * ASZ + 2 * BSZ);

    const int m0   = blockIdx.x * 128;
    const int t    = threadIdx.x;
    const int wid  = t >> 6;
    const int lane = t & 63;
    const int wm   = (wid >> 1) * 64;     // row half
    const int wnb  = (wid & 1) * 128;     // col half
    const int l16  = lane & 15;
    const int quad = lane >> 4;

    // ---- A loader: 2 cp16/thread/iter (8 KB) ----
    const char* aSrc[2]; int aDst[2];
#pragma unroll
    for (int s = 0; s < 2; s++) {
        int L = (s * 4 + wid) * 64 + lane;            // 0..511
        int r = L >> 2;                               // 0..127
        int c = (L & 3) ^ ((r >> 1) & 3);
        int row = m0 + r; if (row > M - 1) row = M - 1;
        aSrc[s] = (const char*)Av + ((size_t)row * KC + (size_t)c * 8) * 2;
        aDst[s] = (s * 4 + wid) * 1024;
    }
    // ---- B loader: 4 cp16/thread/iter (16 KB, all 256 Wb rows) ----
    const char* bSrc[4]; int bDst[4];
#pragma unroll
    for (int s = 0; s < 4; s++) {
        int L = (s * 4 + wid) * 64 + lane;            // 0..1023
        int r = L >> 2;                               // 0..255
        int c = (L & 3) ^ ((r >> 1) & 3);
        bSrc[s] = (const char*)(Wb + (size_t)r * KC + c * 8);
        bDst[s] = (s * 4 + wid) * 1024;
    }

    int aOff[4], bOff[8];
#pragma unroll
    for (int i = 0; i < 4; i++) {
        int ra = wm + i * 16 + l16;
        aOff[i] = ra * 64 + ((quad ^ ((ra >> 1) & 3)) * 16);
    }
#pragma unroll
    for (int j = 0; j < 8; j++) {
        int rb = wnb + j * 16 + l16;                  // 0..255
        bOff[j] = rb * 64 + ((quad ^ ((rb >> 1) & 3)) * 16);
    }

    // fused BN finalize -> scale/shift in LDS (drained before barrier)
    if (t < HIDC) {
        float sum = 0.f, sumsq = 0.f;
        for (int r = 0; r < NREP; r++) {
            sum   += stats[r * 256 + t];
            sumsq += stats[r * 256 + HIDC + t];
        }
        float invM = 1.0f / (float)M;
        float mean = sum * invM;
        float var  = sumsq * invM - mean * mean;
        float s = rsqrtf(var + BN_EPSC) * g[t];
        scS[t] = s;
        scS[HIDC + t] = be[t] - mean * s;
    }
    __syncthreads();

    f32x4 acc[4][8] = {};

#pragma unroll
    for (int s = 0; s < 2; s++) cp16(aSrc[s], Asm + aDst[s]);
#pragma unroll
    for (int s = 0; s < 4; s++) cp16(bSrc[s], Bsm + bDst[s]);

    for (int it = 0; it < NK; ++it) {
        if (it + 1 < NK) {
            const size_t ka = (size_t)(it + 1) * 64;
            const int nb = (it + 1) & 1;
#pragma unroll
            for (int s = 0; s < 2; s++) cp16(aSrc[s] + ka, Asm + nb * ASZ + aDst[s]);
#pragma unroll
            for (int s = 0; s < 4; s++) cp16(bSrc[s] + ka, Bsm + nb * BSZ + bDst[s]);
            asm volatile("s_waitcnt vmcnt(6)" ::: "memory");
        } else {
            asm volatile("s_waitcnt vmcnt(0)" ::: "memory");
        }
        asm volatile("s_barrier" ::: "memory");

        const unsigned char* Ab = Asm + (it & 1) * ASZ;
        const unsigned char* Bb = Bsm + (it & 1) * BSZ;
        bf16x8 af[4], bfr[8];
        float4 s0 = *(const float4*)&scS[it * 32 + quad * 8];
        float4 s1 = *(const float4*)&scS[it * 32 + quad * 8 + 4];
        float4 h0 = *(const float4*)&scS[HIDC + it * 32 + quad * 8];
        float4 h1 = *(const float4*)&scS[HIDC + it * 32 + quad * 8 + 4];
        float ss[8] = {s0.x, s0.y, s0.z, s0.w, s1.x, s1.y, s1.z, s1.w};
        float hh[8] = {h0.x, h0.y, h0.z, h0.w, h1.x, h1.y, h1.z, h1.w};
#pragma unroll
        for (int i = 0; i < 4; i++) {
            bf16x8 raw = *(const bf16x8*)(Ab + aOff[i]);
#pragma unroll
            for (int e = 0; e < 8; e++)
                af[i][e] = (bf16_t)fmaxf(fmaf((float)raw[e], ss[e], hh[e]), 0.0f);
        }
#pragma unroll
        for (int j = 0; j < 8; j++)
            bfr[j] = *(const bf16x8*)(Bb + bOff[j]);
#pragma unroll
        for (int i = 0; i < 4; i++)
#pragma unroll
            for (int j = 0; j < 8; j++)
                acc[i][j] = mfma_16x16x32_bf16(af[i], bfr[j], acc[i][j]);

        asm volatile("s_barrier" ::: "memory");
    }

    bf16_t* C = (wid & 1) ? Cr : Cl;
#pragma unroll
    for (int i = 0; i < 4; i++) {
        int rowb = m0 + wm + i * 16 + quad * 4;
#pragma unroll
        for (int j = 0; j < 8; j++) {
            int colh = j * 16 + l16;
#pragma unroll
            for (int rr = 0; rr < 4; rr++) {
                int row = rowb + rr;
                if (row < M) C[(size_t)row * HIDC + colh] = (bf16_t)acc[i][j][rr];
            }
        }
    }
}

// ---------- fused init: weight converts + zero degi/stats ----------
__global__ void init_kernel(const float* __restrict__ W1l, const float* __restrict__ W1r,
                            const float* __restrict__ W2l, const float* __restrict__ W2r,
                            const float* __restrict__ W3l, const float* __restrict__ W3r,
                            bf16_t* __restrict__ Wb1, bf16_t* __restrict__ Wb2,
                            bf16_t* __restrict__ Wb3,
                            int* __restrict__ degi, float* __restrict__ stats)
{
    const int NW1 = 128 * IN_DIMC;
    const int NW2 = 128 * HIDC;
    const int NS  = 3 * NREP * 256;
    int j = blockIdx.x * blockDim.x + threadIdx.x;
    if (j < 2 * NW1) { Wb1[j] = (bf16_t)((j < NW1) ? W1l[j] : W1r[j - NW1]); return; }
    j -= 2 * NW1;
    if (j < 2 * NW2) { Wb2[j] = (bf16_t)((j < NW2) ? W2l[j] : W2r[j - NW2]); return; }
    j -= 2 * NW2;
    if (j < 2 * NW2) { Wb3[j] = (bf16_t)((j < NW2) ? W3l[j] : W3r[j - NW2]); return; }
    j -= 2 * NW2;
    if (j < NS) { stats[j] = 0.0f; return; }
    j -= NS;
    if (j < N_NODESC) degi[j] = 0;
}

// ---------- CSR build ----------
__global__ void degi_kernel(const int* __restrict__ ei, int* __restrict__ degi) {
    int e = blockIdx.x * blockDim.x + threadIdx.x;
    if (e < N_EDGESC) atomicAdd(&degi[ei[N_EDGESC + e]], 1);
}

__global__ __launch_bounds__(256) void scan1_kernel(const int* __restrict__ degi,
                                                    int* __restrict__ local,
                                                    int* __restrict__ partials)
{
    __shared__ int tmp[256];
    const int t = threadIdx.x;
    const int i = blockIdx.x * 256 + t;
    int v = (i < N_NODESC) ? degi[i] : 0;
    tmp[t] = v;
    __syncthreads();
    for (int off = 1; off < 256; off <<= 1) {
        int u = (t >= off) ? tmp[t - off] : 0;
        __syncthreads();
        tmp[t] += u;
        __syncthreads();
    }
    if (i < N_NODESC) local[i] = tmp[t] - v;
    if (t == 255) partials[blockIdx.x] = tmp[255];
}

// scan3 with the 196-partial scan folded in (replaces the scan2 dispatch)
__global__ __launch_bounds__(256) void scan3_kernel(const int* __restrict__ local,
                                                    const int* __restrict__ partials,
                                                    int* __restrict__ rowptr,
                                                    int* __restrict__ cursor)
{
    __shared__ int inc[256];
    __shared__ int orig[256];
    const int t = threadIdx.x;
    int v = (t < SCAN_NB) ? partials[t] : 0;
    inc[t] = v; orig[t] = v;
    __syncthreads();
    for (int off = 1; off < 256; off <<= 1) {
        int u = (t >= off) ? inc[t - off] : 0;
        __syncthreads();
        inc[t] += u;
        __syncthreads();
    }
    const int boff = inc[blockIdx.x] - orig[blockIdx.x];   // exclusive offset, broadcast
    const int i = blockIdx.x * 256 + t;
    if (i < N_NODESC) {
        int r = local[i] + boff;
        rowptr[i] = r;
        cursor[i] = r;
    }
    if (i == 0) rowptr[N_NODESC] = N_EDGESC;
}

__global__ void fill_kernel(const int* __restrict__ ei, int* __restrict__ cursor,
                            int* __restrict__ col) {
    int e = blockIdx.x * blockDim.x + threadIdx.x;
    if (e >= N_EDGESC) return;
    int d = ei[N_EDGESC + e];
    int pos = atomicAdd(&cursor[d], 1);
    col[pos] = ei[e];
}

// ---------- fused CSR-gather mean-agg + bias + Pr + BN partial sums ----------
// R5-proven round-based interleave (REVERTED from R7: breaking idx uniformity
// cost +85us -- col loads must stay wave-uniform/scalar so each gather
// instruction covers ONE contiguous 256B row). NO device-scope fences.
__global__ __launch_bounds__(128) void agg_combine_kernel(const int* __restrict__ rowptr,
                                                          const int* __restrict__ col,
                                                          const bf16_t* __restrict__ Plb,
                                                          const bf16_t* __restrict__ Prb,
                                                          const float* __restrict__ bias,
                                                          bf16_t* __restrict__ Hb,
                                                          float* __restrict__ stats, int M)
{
    const int lane = threadIdx.x & 63;
    const int wv   = threadIdx.x >> 6;
    const int c0   = lane * 2;
    const float b0 = bias[c0], b1v = bias[c0 + 1];
    const int n0 = blockIdx.x * NB_AGG + wv * (NB_AGG / 2);

    int lo[4], hi[4], pos[4];
    bf16x2 pr[4];
#pragma unroll
    for (int r = 0; r < 4; r++) {
        int n = n0 + r;
        lo[r] = (n < M) ? rowptr[n] : 0;
        hi[r] = (n < M) ? rowptr[n + 1] : 0;
        pos[r] = lo[r];
        if (n < M) pr[r] = *(const bf16x2*)&Prb[(size_t)n * HIDC + c0];
        else { pr[r][0] = (bf16_t)0.f; pr[r][1] = (bf16_t)0.f; }
    }

    float a0[4] = {0.f, 0.f, 0.f, 0.f}, a1[4] = {0.f, 0.f, 0.f, 0.f};

    for (;;) {
        int cnt[4];
        bool any = false;
#pragma unroll
        for (int r = 0; r < 4; r++) {
            int c = hi[r] - pos[r];
            cnt[r] = (c > 8) ? 8 : c;
            if (cnt[r] > 0) any = true;
        }
        if (!any) break;

        bf16x2 v[4][8];
#pragma unroll
        for (int r = 0; r < 4; r++) {
            if (cnt[r] > 0) {                       // wave-uniform branch
                int idx[8];
#pragma unroll
                for (int j = 0; j < 8; j++) {
                    int ee = pos[r] + j;
                    if (ee > hi[r] - 1) ee = hi[r] - 1;
                    idx[j] = col[ee];               // broadcast loads
                }
#pragma unroll
                for (int j = 0; j < 8; j++)
                    v[r][j] = *(const bf16x2*)&Plb[(size_t)idx[j] * HIDC + c0];
            }
        }
#pragma unroll
        for (int r = 0; r < 4; r++) {
            if (cnt[r] > 0) {
#pragma unroll
                for (int j = 0; j < 8; j++)
                    if (j < cnt[r]) { a0[r] += (float)v[r][j][0]; a1[r] += (float)v[r][j][1]; }
                pos[r] += cnt[r];
            }
        }
    }

    float s0 = 0.f, s1 = 0.f, q0 = 0.f, q1 = 0.f;
#pragma unroll
    for (int r = 0; r < 4; r++) {
        int n = n0 + r;
        if (n < M) {
            int d = hi[r] - lo[r];
            float inv = 1.0f / (float)(d > 0 ? d : 1);
            float pre0 = fmaf(a0[r], inv, b0) + (float)pr[r][0];
            float pre1 = fmaf(a1[r], inv, b1v) + (float)pr[r][1];
            bf16x2 hv; hv[0] = (bf16_t)pre0; hv[1] = (bf16_t)pre1;
            *(bf16x2*)&Hb[(size_t)n * HIDC + c0] = hv;
            s0 += pre0; s1 += pre1; q0 += pre0 * pre0; q1 += pre1 * pre1;
        }
    }
    const int rep = (blockIdx.x * 2 + wv) & (NREP - 1);
    atomicAdd(&stats[rep * 256 + c0], s0);
    atomicAdd(&stats[rep * 256 + c0 + 1], s1);
    atomicAdd(&stats[rep * 256 + HIDC + c0], q0);
    atomicAdd(&stats[rep * 256 + HIDC + c0 + 1], q1);
}

// ---------- fused BN3-finalize + pool + linear head ----------
__global__ __launch_bounds__(128) void poolhead_kernel(const bf16_t* __restrict__ Hb,
                                                       const float* __restrict__ stats,
                                                       const float* __restrict__ g,
                                                       const float* __restrict__ be,
                                                       const int* __restrict__ batch,
                                                       const float* __restrict__ Wlin,
                                                       const float* __restrict__ blin,
                                                       float* __restrict__ out, int M)
{
    __shared__ float sp[HIDC];
    int gph = blockIdx.x;
    int c   = threadIdx.x;
    float sum = 0.f, sumsq = 0.f;
    for (int r = 0; r < NREP; r++) {
        sum   += stats[r * 256 + c];
        sumsq += stats[r * 256 + HIDC + c];
    }
    float invM = 1.0f / (float)M;
    float mean = sum * invM;
    float var  = sumsq * invM - mean * mean;
    float s = rsqrtf(var + BN_EPSC) * g[c];
    float h = be[c] - mean * s;

    int lo = 0, hi = M;
    while (lo < hi) { int m = (lo + hi) >> 1; if (batch[m] < gph) lo = m + 1; else hi = m; }
    int lo2 = lo, hi2 = M;
    while (lo2 < hi2) { int m = (lo2 + hi2) >> 1; if (batch[m] < gph + 1) lo2 = m + 1; else hi2 = m; }
    float mx = -INFINITY;
    for (int rr = lo; rr < lo2; rr++)
        mx = fmaxf(mx, fmaf((float)Hb[(size_t)rr * HIDC + c], s, h));
    sp[c] = mx;
    __syncthreads();
    if (c < NCLSC) {
        float acc = blin[c];
        for (int k = 0; k < HIDC; k++) acc += sp[k] * Wlin[c * HIDC + k];
        out[gph * NCLSC + c] = acc;
    }
}

extern "C" void kernel_launch(void* const* d_in, const int* in_sizes, int n_in,
                              void* d_out, int out_size, void* d_ws, size_t ws_size,
                              hipStream_t stream)
{
    const float* x     = (const float*)d_in[0];
    const int*   ei    = (const int*)d_in[1];
    const int*   batch = (const int*)d_in[2];
    const float* W1l = (const float*)d_in[3];
    const float* b1  = (const float*)d_in[4];
    const float* W1r = (const float*)d_in[5];
    const float* g1  = (const float*)d_in[6];
    const float* be1 = (const float*)d_in[7];
    const float* W2l = (const float*)d_in[8];
    const float* b2  = (const float*)d_in[9];
    const float* W2r = (const float*)d_in[10];
    const float* g2  = (const float*)d_in[11];
    const float* be2 = (const float*)d_in[12];
    const float* W3l = (const float*)d_in[13];
    const float* b3  = (const float*)d_in[14];
    const float* W3r = (const float*)d_in[15];
    const float* g3  = (const float*)d_in[16];
    const float* be3 = (const float*)d_in[17];
    const float* Wlin = (const float*)d_in[18];
    const float* blin = (const float*)d_in[19];

    const int M = N_NODESC;

    // workspace carve (16B aligned)
    char* w = (char*)d_ws;
    bf16_t* Plb  = (bf16_t*)w;  w += (size_t)M * HIDC * 2;
    bf16_t* Prb  = (bf16_t*)w;  w += (size_t)M * HIDC * 2;
    bf16_t* Hb   = (bf16_t*)w;  w += (size_t)M * HIDC * 2;
    bf16_t* Wb1  = (bf16_t*)w;  w += (size_t)256 * IN_DIMC * 2;
    bf16_t* Wb2  = (bf16_t*)w;  w += (size_t)256 * HIDC * 2;
    bf16_t* Wb3  = (bf16_t*)w;  w += (size_t)256 * HIDC * 2;
    int*   rowptr= (int*)w;     w += (size_t)(M + 16) * 4;
    int*   col   = (int*)w;     w += (size_t)N_EDGESC * 4;
    int*   cursor= (int*)w;     w += (size_t)M * 4;
    int*   degi  = (int*)w;     w += (size_t)M * 4;
    int*   slocal= (int*)w;     w += (size_t)M * 4;
    int*   spart = (int*)w;     w += 256 * 4;
    float* stats = (float*)w;   w += (size_t)3 * NREP * 256 * 4;   // zeroed in init

    float* stats1 = stats;
    float* stats2 = stats + NREP * 256;
    float* stats3 = stats + 2 * NREP * 256;

    const int nP128 = (M + 127) / 128;                  // 391
    const dim3 l1_grid(nP128);                          // fused 128x256 tile
    const dim3 hid_grid(nP128);                         // fused 128x256 tile
    const int agg_blocks = (M + NB_AGG - 1) / NB_AGG;
    const int init_total = 2 * 128 * IN_DIMC + 4 * 128 * HIDC + 3 * NREP * 256 + M;

    // ---- init (weights + zeros, one dispatch) ----
    init_kernel<<<(init_total + 255) / 256, 256, 0, stream>>>(W1l, W1r, W2l, W2r, W3l, W3r,
                                                              Wb1, Wb2, Wb3, degi, stats);
    // ---- CSR build (4 dispatches) ----
    degi_kernel<<<(N_EDGESC + 255) / 256, 256, 0, stream>>>(ei, degi);
    scan1_kernel<<<SCAN_NB, 256, 0, stream>>>(degi, slocal, spart);
    scan3_kernel<<<SCAN_NB, 256, 0, stream>>>(slocal, spart, rowptr, cursor);
    fill_kernel<<<(N_EDGESC + 255) / 256, 256, 0, stream>>>(ei, cursor, col);

    // ---- layer 1 (K=768, fused 128x256 tile, R5 config) ----
    gemm_l1_kernel<<<l1_grid, 256, 0, stream>>>(x, Wb1, Plb, Prb, M);
    agg_combine_kernel<<<agg_blocks, 128, 0, stream>>>(rowptr, col, Plb, Prb, b1, Hb, stats1, M);

    // ---- layer 2 (K=128; BN1 finalize + BN1+ReLU fused into the GEMM) ----
    gemm_hid_kernel<<<hid_grid, 256, 0, stream>>>(Hb, Wb2, stats1, g1, be1, Plb, Prb, M);
    agg_combine_kernel<<<agg_blocks, 128, 0, stream>>>(rowptr, col, Plb, Prb, b2, Hb, stats2, M);

    // ---- layer 3 (K=128; BN2 finalize + BN2+ReLU fused) ----
    gemm_hid_kernel<<<hid_grid, 256, 0, stream>>>(Hb, Wb3, stats2, g2, be2, Plb, Prb, M);
    agg_combine_kernel<<<agg_blocks, 128, 0, stream>>>(rowptr, col, Plb, Prb, b3, Hb, stats3, M);

    // ---- BN3 finalize + pool + head (one dispatch) ----
    poolhead_kernel<<<N_GRAPHSC, 128, 0, stream>>>(Hb, stats3, g3, be3, batch, Wlin, blin,
                                                   (float*)d_out, M);
}

// Round 10
// 545.969 us; speedup vs baseline: 1.1759x; 1.0282x over previous
//
#include <hip/hip_runtime.h>

#define N_NODESC 50000
#define N_EDGESC 400000
#define N_GRAPHSC 128
#define IN_DIMC 768
#define HIDC 128
#define NCLSC 11
#define BN_EPSC 1e-5f
#define NB_AGG 8
#define NREP 64
#define SCAN_NB ((N_NODESC + 255) / 256)

typedef __bf16 bf16_t;
typedef __bf16 bf16x2 __attribute__((ext_vector_type(2)));
typedef __bf16 bf16x8 __attribute__((ext_vector_type(8)));
typedef float f32x4 __attribute__((ext_vector_type(4)));

typedef __attribute__((address_space(1))) void glb_void;
typedef __attribute__((address_space(3))) void lds_void;

__device__ __forceinline__ void cp16(const void* g, void* l) {
    // async global->LDS, 16B/lane; LDS dst = wave-uniform base + lane*16
    __builtin_amdgcn_global_load_lds((glb_void*)g, (lds_void*)l, 16, 0, 0);
}

__device__ __forceinline__ f32x4 mfma_16x16x32_bf16(bf16x8 a, bf16x8 b, f32x4 c) {
    return __builtin_amdgcn_mfma_f32_16x16x32_bf16(a, b, c, 0, 0, 0);
}

// ---------------- layer-1 GEMM (R5-proven config):
// [Cl|Cr] = A[M,768]fp32 @ Wb^T, Wb[256,768]bf16. 128x256 tile, 256 threads,
// 391 blocks -> 2 blocks/CU. R6 lesson: staged-byte model holds only at
// >=2 blocks/CU (1 block/CU exposes the depth-1 convoy stall).
__global__ __launch_bounds__(256, 2) void gemm_l1_kernel(const float* __restrict__ Av,
                                                         const bf16_t* __restrict__ Wb,
                                                         bf16_t* __restrict__ Cl,
                                                         bf16_t* __restrict__ Cr,
                                                         int M)
{
    constexpr int KC  = IN_DIMC;          // 768
    constexpr int NK  = KC / 32;          // 24
    constexpr int ASZ = 16384;            // fp32 128x32
    constexpr int BSZ = 16384;            // bf16 256x32
    __shared__ __align__(16) unsigned char smem[2 * ASZ + 2 * BSZ];
    unsigned char* Asm = smem;
    unsigned char* Bsm = smem + 2 * ASZ;

    const int m0   = blockIdx.x * 128;
    const int t    = threadIdx.x;
    const int wid  = t >> 6;
    const int lane = t & 63;
    const int wm   = (wid >> 1) * 64;     // row half
    const int l16  = lane & 15;
    const int quad = lane >> 4;

    // ---- A loader: 4 chunks/wave, 16 KB/iter, XOR swizzle on global side ----
    const char* aSrc[4]; int aDst[4];
#pragma unroll
    for (int s = 0; s < 4; s++) {
        int L = (s * 4 + wid) * 64 + lane;            // 16B slot; LDS byte = L*16
        int r = L >> 3;                               // 0..127
        int c = (L & 7) ^ (r & 7);                    // 8 chunks per 128B row
        int row = m0 + r; if (row > M - 1) row = M - 1;  // clamp; never stored
        aSrc[s] = (const char*)Av + ((size_t)row * KC + (size_t)c * 4) * 4;
        aDst[s] = (s * 4 + wid) * 1024;
    }
    // ---- B loader: 4 chunks/wave, 16 KB/iter (all 256 Wb rows) ----
    const char* bSrc[4]; int bDst[4];
#pragma unroll
    for (int s = 0; s < 4; s++) {
        int L = (s * 4 + wid) * 64 + lane;
        int r = L >> 2;                               // 0..255
        int c = (L & 3) ^ ((r >> 1) & 3);
        bSrc[s] = (const char*)(Wb + (size_t)r * KC + c * 8);
        bDst[s] = (s * 4 + wid) * 1024;
    }

    // ---- fragment LDS byte offsets ----
    int aOff[4][2], bOff[8];
#pragma unroll
    for (int i = 0; i < 4; i++) {
        int ra = wm + i * 16 + l16;
        aOff[i][0] = ra * 128 + (((2 * quad)     ^ (ra & 7)) * 16);
        aOff[i][1] = ra * 128 + (((2 * quad + 1) ^ (ra & 7)) * 16);
    }
    const int wnb = (wid & 1) * 128;                  // output-col half
#pragma unroll
    for (int j = 0; j < 8; j++) {
        int rb = wnb + j * 16 + l16;                  // 0..255
        bOff[j] = rb * 64 + ((quad ^ ((rb >> 1) & 3)) * 16);
    }

    f32x4 acc[4][8] = {};

    // ---- depth-1 double buffer (R0-proven schedule) ----
#pragma unroll
    for (int s = 0; s < 4; s++) cp16(aSrc[s], Asm + aDst[s]);
#pragma unroll
    for (int s = 0; s < 4; s++) cp16(bSrc[s], Bsm + bDst[s]);

    for (int it = 0; it < NK; ++it) {
        if (it + 1 < NK) {
            const size_t ka = (size_t)(it + 1) * 128;
            const size_t kb = (size_t)(it + 1) * 64;
            const int nb = (it + 1) & 1;
#pragma unroll
            for (int s = 0; s < 4; s++) cp16(aSrc[s] + ka, Asm + nb * ASZ + aDst[s]);
#pragma unroll
            for (int s = 0; s < 4; s++) cp16(bSrc[s] + kb, Bsm + nb * BSZ + bDst[s]);
            asm volatile("s_waitcnt vmcnt(8)" ::: "memory");   // drain iter-it only
        } else {
            asm volatile("s_waitcnt vmcnt(0)" ::: "memory");
        }
        asm volatile("s_barrier" ::: "memory");

        const unsigned char* Ab = Asm + (it & 1) * ASZ;
        const unsigned char* Bb = Bsm + (it & 1) * BSZ;
        bf16x8 af[4], bfr[8];
#pragma unroll
        for (int i = 0; i < 4; i++) {
            float4 u0 = *(const float4*)(Ab + aOff[i][0]);
            float4 u1 = *(const float4*)(Ab + aOff[i][1]);
            af[i][0] = (bf16_t)u0.x; af[i][1] = (bf16_t)u0.y;
            af[i][2] = (bf16_t)u0.z; af[i][3] = (bf16_t)u0.w;
            af[i][4] = (bf16_t)u1.x; af[i][5] = (bf16_t)u1.y;
            af[i][6] = (bf16_t)u1.z; af[i][7] = (bf16_t)u1.w;
        }
#pragma unroll
        for (int j = 0; j < 8; j++)
            bfr[j] = *(const bf16x8*)(Bb + bOff[j]);
#pragma unroll
        for (int i = 0; i < 4; i++)
#pragma unroll
            for (int j = 0; j < 8; j++)
                acc[i][j] = mfma_16x16x32_bf16(af[i], bfr[j], acc[i][j]);

        asm volatile("s_barrier" ::: "memory");   // protect buf reused next iter
    }

    // C/D layout (m89-verified); wave col-half -> Cl or Cr directly
    bf16_t* C = (wid & 1) ? Cr : Cl;
#pragma unroll
    for (int i = 0; i < 4; i++) {
        int rowb = m0 + wm + i * 16 + quad * 4;
#pragma unroll
        for (int j = 0; j < 8; j++) {
            int colh = j * 16 + l16;
#pragma unroll
            for (int rr = 0; rr < 4; rr++) {
                int row = rowb + rr;
                if (row < M) C[(size_t)row * HIDC + colh] = (bf16_t)acc[i][j][rr];
            }
        }
    }
}

// ---------------- hidden-layer GEMM (K=128): R5-proven structure (R8's fused
// tile was neutral-to-negative; reverted). A bf16 via cp16 depth-2 triple
// buffer; BN finalize in-kernel; BN+ReLU post-LDS-read. Pair-colocation grid.
__global__ __launch_bounds__(256) void gemm_hid_kernel(const bf16_t* __restrict__ Av,
                                                       const bf16_t* __restrict__ Wb,
                                                       const float* __restrict__ stats,
                                                       const float* __restrict__ g,
                                                       const float* __restrict__ be,
                                                       bf16_t* __restrict__ Cl,
                                                       bf16_t* __restrict__ Cr,
                                                       int M)
{
    constexpr int KC  = HIDC;             // 128
    constexpr int NK  = KC / 32;          // 4
    constexpr int ASZ = 8192;
    constexpr int BSZ = 8192;
    __shared__ __align__(16) unsigned char smem[3 * ASZ + 3 * BSZ + 1024];
    unsigned char* Asm = smem;
    unsigned char* Bsm = smem + 3 * ASZ;
    float* scS = (float*)(smem + 3 * ASZ + 3 * BSZ);

    const int bid  = blockIdx.x;
    const int p    = ((bid >> 4) << 3) + (bid & 7);
    const int half = (bid >> 3) & 1;
    if (p * 128 >= M) return;
    const int m0 = p * 128;

    const int t    = threadIdx.x;
    const int wid  = t >> 6;
    const int lane = t & 63;
    const int wm   = (wid >> 1) * 64;
    const int wn   = (wid & 1) * 64;
    const int l16  = lane & 15;
    const int quad = lane >> 4;

    const char* bSrc[2]; int bDst[2];
#pragma unroll
    for (int s = 0; s < 2; s++) {
        int L = (s * 4 + wid) * 64 + lane;
        int r = L >> 2;
        int c = (L & 3) ^ ((r >> 1) & 3);
        bSrc[s] = (const char*)(Wb + (size_t)(half * 128 + r) * KC + c * 8);
        bDst[s] = (s * 4 + wid) * 1024;
    }
    const char* aSrc[2]; int aDst[2];
#pragma unroll
    for (int s = 0; s < 2; s++) {
        int L = (s * 4 + wid) * 64 + lane;
        int r = L >> 2;
        int c = (L & 3) ^ ((r >> 1) & 3);
        int row = m0 + r; if (row > M - 1) row = M - 1;
        aSrc[s] = (const char*)Av + ((size_t)row * KC + (size_t)c * 8) * 2;
        aDst[s] = (s * 4 + wid) * 1024;
    }

    int aOff[4], bOff[4];
#pragma unroll
    for (int i = 0; i < 4; i++) {
        int ra = wm + i * 16 + l16;
        aOff[i] = ra * 64 + ((quad ^ ((ra >> 1) & 3)) * 16);
        int rb = wn + i * 16 + l16;
        bOff[i] = rb * 64 + ((quad ^ ((rb >> 1) & 3)) * 16);
    }

    // fused BN finalize -> scale/shift in LDS (drained before barrier)
    if (t < HIDC) {
        float sum = 0.f, sumsq = 0.f;
        for (int r = 0; r < NREP; r++) {
            sum   += stats[r * 256 + t];
            sumsq += stats[r * 256 + HIDC + t];
        }
        float invM = 1.0f / (float)M;
        float mean = sum * invM;
        float var  = sumsq * invM - mean * mean;
        float s = rsqrtf(var + BN_EPSC) * g[t];
        scS[t] = s;
        scS[HIDC + t] = be[t] - mean * s;
    }
    __syncthreads();

    f32x4 acc[4][4] = {};

#pragma unroll
    for (int s = 0; s < 2; s++) cp16(aSrc[s], Asm + aDst[s]);
#pragma unroll
    for (int s = 0; s < 2; s++) cp16(bSrc[s], Bsm + bDst[s]);
#pragma unroll
    for (int s = 0; s < 2; s++) cp16(aSrc[s] + 64, Asm + ASZ + aDst[s]);
#pragma unroll
    for (int s = 0; s < 2; s++) cp16(bSrc[s] + 64, Bsm + BSZ + bDst[s]);

    for (int it = 0; it < NK; ++it) {
        if (it + 2 < NK) {
            const size_t kb2 = (size_t)(it + 2) * 64;
            const int nb = (it + 2) % 3;
#pragma unroll
            for (int s = 0; s < 2; s++) cp16(aSrc[s] + kb2, Asm + nb * ASZ + aDst[s]);
#pragma unroll
            for (int s = 0; s < 2; s++) cp16(bSrc[s] + kb2, Bsm + nb * BSZ + bDst[s]);
            asm volatile("s_waitcnt vmcnt(8)" ::: "memory");
        } else if (it + 1 < NK) {
            asm volatile("s_waitcnt vmcnt(4)" ::: "memory");
        } else {
            asm volatile("s_waitcnt vmcnt(0)" ::: "memory");
        }
        asm volatile("s_barrier" ::: "memory");

        const unsigned char* Ab = Asm + (it % 3) * ASZ;
        const unsigned char* Bb = Bsm + (it % 3) * BSZ;
        bf16x8 af[4], bfr[4];
        float4 s0 = *(const float4*)&scS[it * 32 + quad * 8];
        float4 s1 = *(const float4*)&scS[it * 32 + quad * 8 + 4];
        float4 h0 = *(const float4*)&scS[HIDC + it * 32 + quad * 8];
        float4 h1 = *(const float4*)&scS[HIDC + it * 32 + quad * 8 + 4];
        float ss[8] = {s0.x, s0.y, s0.z, s0.w, s1.x, s1.y, s1.z, s1.w};
        float hh[8] = {h0.x, h0.y, h0.z, h0.w, h1.x, h1.y, h1.z, h1.w};
#pragma unroll
        for (int i = 0; i < 4; i++) {
            bf16x8 raw = *(const bf16x8*)(Ab + aOff[i]);
#pragma unroll
            for (int e = 0; e < 8; e++)
                af[i][e] = (bf16_t)fmaxf(fmaf((float)raw[e], ss[e], hh[e]), 0.0f);
        }
#pragma unroll
        for (int j = 0; j < 4; j++)
            bfr[j] = *(const bf16x8*)(Bb + bOff[j]);
#pragma unroll
        for (int i = 0; i < 4; i++)
#pragma unroll
            for (int j = 0; j < 4; j++)
                acc[i][j] = mfma_16x16x32_bf16(af[i], bfr[j], acc[i][j]);

        asm volatile("s_barrier" ::: "memory");
    }

    bf16_t* C = half ? Cr : Cl;
#pragma unroll
    for (int i = 0; i < 4; i++) {
        int rowb = m0 + wm + i * 16 + quad * 4;
#pragma unroll
        for (int j = 0; j < 4; j++) {
            int colh = wn + j * 16 + l16;
#pragma unroll
            for (int rr = 0; rr < 4; rr++) {
                int row = rowb + rr;
                if (row < M) C[(size_t)row * HIDC + colh] = (bf16_t)acc[i][j][rr];
            }
        }
    }
}

// ---------- fused init: weight converts + zero degi/stats ----------
__global__ void init_kernel(const float* __restrict__ W1l, const float* __restrict__ W1r,
                            const float* __restrict__ W2l, const float* __restrict__ W2r,
                            const float* __restrict__ W3l, const float* __restrict__ W3r,
                            bf16_t* __restrict__ Wb1, bf16_t* __restrict__ Wb2,
                            bf16_t* __restrict__ Wb3,
                            int* __restrict__ degi, float* __restrict__ stats)
{
    const int NW1 = 128 * IN_DIMC;
    const int NW2 = 128 * HIDC;
    const int NS  = 3 * NREP * 256;
    int j = blockIdx.x * blockDim.x + threadIdx.x;
    if (j < 2 * NW1) { Wb1[j] = (bf16_t)((j < NW1) ? W1l[j] : W1r[j - NW1]); return; }
    j -= 2 * NW1;
    if (j < 2 * NW2) { Wb2[j] = (bf16_t)((j < NW2) ? W2l[j] : W2r[j - NW2]); return; }
    j -= 2 * NW2;
    if (j < 2 * NW2) { Wb3[j] = (bf16_t)((j < NW2) ? W3l[j] : W3r[j - NW2]); return; }
    j -= 2 * NW2;
    if (j < NS) { stats[j] = 0.0f; return; }
    j -= NS;
    if (j < N_NODESC) degi[j] = 0;
}

// ---------- CSR build ----------
__global__ void degi_kernel(const int* __restrict__ ei, int* __restrict__ degi) {
    int e = blockIdx.x * blockDim.x + threadIdx.x;
    if (e < N_EDGESC) atomicAdd(&degi[ei[N_EDGESC + e]], 1);
}

__global__ __launch_bounds__(256) void scan1_kernel(const int* __restrict__ degi,
                                                    int* __restrict__ local,
                                                    int* __restrict__ partials)
{
    __shared__ int tmp[256];
    const int t = threadIdx.x;
    const int i = blockIdx.x * 256 + t;
    int v = (i < N_NODESC) ? degi[i] : 0;
    tmp[t] = v;
    __syncthreads();
    for (int off = 1; off < 256; off <<= 1) {
        int u = (t >= off) ? tmp[t - off] : 0;
        __syncthreads();
        tmp[t] += u;
        __syncthreads();
    }
    if (i < N_NODESC) local[i] = tmp[t] - v;
    if (t == 255) partials[blockIdx.x] = tmp[255];
}

// scan3 with the 196-partial scan folded in (replaces the scan2 dispatch)
__global__ __launch_bounds__(256) void scan3_kernel(const int* __restrict__ local,
                                                    const int* __restrict__ partials,
                                                    int* __restrict__ rowptr,
                                                    int* __restrict__ cursor)
{
    __shared__ int inc[256];
    __shared__ int orig[256];
    const int t = threadIdx.x;
    int v = (t < SCAN_NB) ? partials[t] : 0;
    inc[t] = v; orig[t] = v;
    __syncthreads();
    for (int off = 1; off < 256; off <<= 1) {
        int u = (t >= off) ? inc[t - off] : 0;
        __syncthreads();
        inc[t] += u;
        __syncthreads();
    }
    const int boff = inc[blockIdx.x] - orig[blockIdx.x];   // exclusive offset, broadcast
    const int i = blockIdx.x * 256 + t;
    if (i < N_NODESC) {
        int r = local[i] + boff;
        rowptr[i] = r;
        cursor[i] = r;
    }
    if (i == 0) rowptr[N_NODESC] = N_EDGESC;
}

__global__ void fill_kernel(const int* __restrict__ ei, int* __restrict__ cursor,
                            int* __restrict__ col) {
    int e = blockIdx.x * blockDim.x + threadIdx.x;
    if (e >= N_EDGESC) return;
    int d = ei[N_EDGESC + e];
    int pos = atomicAdd(&cursor[d], 1);
    col[pos] = ei[e];
}

// ---------- fused CSR-gather mean-agg + bias + Pr + BN partial sums ----------
// R9: counted-rounds loop + NEXT-ROUND INDEX PREFETCH. rounds is computable
// from rowptr alone (wave-uniform), so round rd+1's col[] loads issue DURING
// round rd's gathers -- the col->gather dependent chain (~300-500cy/round)
// leaves the critical path. Gathers keep R5's wave-uniform idx (R7 lesson:
// one 256B row per instruction, never per-lane divergent addresses).
__global__ __launch_bounds__(128) void agg_combine_kernel(const int* __restrict__ rowptr,
                                                          const int* __restrict__ col,
                                                          const bf16_t* __restrict__ Plb,
                                                          const bf16_t* __restrict__ Prb,
                                                          const float* __restrict__ bias,
                                                          bf16_t* __restrict__ Hb,
                                                          float* __restrict__ stats, int M)
{
    const int lane = threadIdx.x & 63;
    const int wv   = threadIdx.x >> 6;
    const int c0   = lane * 2;
    const float b0 = bias[c0], b1v = bias[c0 + 1];
    const int n0 = blockIdx.x * NB_AGG + wv * (NB_AGG / 2);

    int lo[4], hi[4];
    bf16x2 pr[4];
#pragma unroll
    for (int r = 0; r < 4; r++) {
        int n = n0 + r;
        lo[r] = (n < M) ? rowptr[n] : 0;
        hi[r] = (n < M) ? rowptr[n + 1] : 0;
        if (n < M) pr[r] = *(const bf16x2*)&Prb[(size_t)n * HIDC + c0];
        else { pr[r][0] = (bf16_t)0.f; pr[r][1] = (bf16_t)0.f; }
    }

    int rounds = 0;
#pragma unroll
    for (int r = 0; r < 4; r++) {
        int rr = (hi[r] - lo[r] + 7) >> 3;
        if (rr > rounds) rounds = rr;
    }

    float a0[4] = {0.f, 0.f, 0.f, 0.f}, a1[4] = {0.f, 0.f, 0.f, 0.f};
    int idxC[4][8] = {}, idxN[4][8] = {};   // zero-init: rotation may read
                                            // rows whose prefetch was skipped
                                            // (never used for addressing)

    // prologue: round-0 indices (uniform branch; broadcast loads)
#pragma unroll
    for (int r = 0; r < 4; r++) {
        if (lo[r] < hi[r]) {
#pragma unroll
            for (int j = 0; j < 8; j++) {
                int ee = lo[r] + j;
                if (ee > hi[r] - 1) ee = hi[r] - 1;
                idxC[r][j] = col[ee];
            }
        }
    }

    for (int rd = 0; rd < rounds; rd++) {
        // a) prefetch next round's indices (hidden under this round's gathers)
        if (rd + 1 < rounds) {
#pragma unroll
            for (int r = 0; r < 4; r++) {
                int base = lo[r] + (rd + 1) * 8;
                if (base < hi[r]) {            // wave-uniform
#pragma unroll
                    for (int j = 0; j < 8; j++) {
                        int ee = base + j;
                        if (ee > hi[r] - 1) ee = hi[r] - 1;
                        idxN[r][j] = col[ee];
                    }
                }
            }
        }
        // b) gathers for this round (independent 256B-row reads, uniform idx)
        bf16x2 v[4][8];
#pragma unroll
        for (int r = 0; r < 4; r++) {
            int base = lo[r] + rd * 8;
            if (base < hi[r]) {                // wave-uniform
#pragma unroll
                for (int j = 0; j < 8; j++)
                    v[r][j] = *(const bf16x2*)&Plb[(size_t)idxC[r][j] * HIDC + c0];
            }
        }
        // c) accumulate
#pragma unroll
        for (int r = 0; r < 4; r++) {
            int base = lo[r] + rd * 8;
            if (base < hi[r]) {
                int cnt = hi[r] - base; if (cnt > 8) cnt = 8;
#pragma unroll
                for (int j = 0; j < 8; j++)
                    if (j < cnt) { a0[r] += (float)v[r][j][0]; a1[r] += (float)v[r][j][1]; }
            }
        }
        // d) rotate prefetched indices into place
#pragma unroll
        for (int r = 0; r < 4; r++)
#pragma unroll
            for (int j = 0; j < 8; j++) idxC[r][j] = idxN[r][j];
    }

    float s0 = 0.f, s1 = 0.f, q0 = 0.f, q1 = 0.f;
#pragma unroll
    for (int r = 0; r < 4; r++) {
        int n = n0 + r;
        if (n < M) {
            int d = hi[r] - lo[r];
            float inv = 1.0f / (float)(d > 0 ? d : 1);
            float pre0 = fmaf(a0[r], inv, b0) + (float)pr[r][0];
            float pre1 = fmaf(a1[r], inv, b1v) + (float)pr[r][1];
            bf16x2 hv; hv[0] = (bf16_t)pre0; hv[1] = (bf16_t)pre1;
            *(bf16x2*)&Hb[(size_t)n * HIDC + c0] = hv;
            s0 += pre0; s1 += pre1; q0 += pre0 * pre0; q1 += pre1 * pre1;
        }
    }
    const int rep = (blockIdx.x * 2 + wv) & (NREP - 1);
    atomicAdd(&stats[rep * 256 + c0], s0);
    atomicAdd(&stats[rep * 256 + c0 + 1], s1);
    atomicAdd(&stats[rep * 256 + HIDC + c0], q0);
    atomicAdd(&stats[rep * 256 + HIDC + c0 + 1], q1);
}

// ---------- fused BN3-finalize + pool + linear head ----------
__global__ __launch_bounds__(128) void poolhead_kernel(const bf16_t* __restrict__ Hb,
                                                       const float* __restrict__ stats,
                                                       const float* __restrict__ g,
                                                       const float* __restrict__ be,
                                                       const int* __restrict__ batch,
                                                       const float* __restrict__ Wlin,
                                                       const float* __restrict__ blin,
                                                       float* __restrict__ out, int M)
{
    __shared__ float sp[HIDC];
    int gph = blockIdx.x;
    int c   = threadIdx.x;
    float sum = 0.f, sumsq = 0.f;
    for (int r = 0; r < NREP; r++) {
        sum   += stats[r * 256 + c];
        sumsq += stats[r * 256 + HIDC + c];
    }
    float invM = 1.0f / (float)M;
    float mean = sum * invM;
    float var  = sumsq * invM - mean * mean;
    float s = rsqrtf(var + BN_EPSC) * g[c];
    float h = be[c] - mean * s;

    int lo = 0, hi = M;
    while (lo < hi) { int m = (lo + hi) >> 1; if (batch[m] < gph) lo = m + 1; else hi = m; }
    int lo2 = lo, hi2 = M;
    while (lo2 < hi2) { int m = (lo2 + hi2) >> 1; if (batch[m] < gph + 1) lo2 = m + 1; else hi2 = m; }
    float mx = -INFINITY;
    for (int rr = lo; rr < lo2; rr++)
        mx = fmaxf(mx, fmaf((float)Hb[(size_t)rr * HIDC + c], s, h));
    sp[c] = mx;
    __syncthreads();
    if (c < NCLSC) {
        float acc = blin[c];
        for (int k = 0; k < HIDC; k++) acc += sp[k] * Wlin[c * HIDC + k];
        out[gph * NCLSC + c] = acc;
    }
}

extern "C" void kernel_launch(void* const* d_in, const int* in_sizes, int n_in,
                              void* d_out, int out_size, void* d_ws, size_t ws_size,
                              hipStream_t stream)
{
    const float* x     = (const float*)d_in[0];
    const int*   ei    = (const int*)d_in[1];
    const int*   batch = (const int*)d_in[2];
    const float* W1l = (const float*)d_in[3];
    const float* b1  = (const float*)d_in[4];
    const float* W1r = (const float*)d_in[5];
    const float* g1  = (const float*)d_in[6];
    const float* be1 = (const float*)d_in[7];
    const float* W2l = (const float*)d_in[8];
    const float* b2  = (const float*)d_in[9];
    const float* W2r = (const float*)d_in[10];
    const float* g2  = (const float*)d_in[11];
    const float* be2 = (const float*)d_in[12];
    const float* W3l = (const float*)d_in[13];
    const float* b3  = (const float*)d_in[14];
    const float* W3r = (const float*)d_in[15];
    const float* g3  = (const float*)d_in[16];
    const float* be3 = (const float*)d_in[17];
    const float* Wlin = (const float*)d_in[18];
    const float* blin = (const float*)d_in[19];

    const int M = N_NODESC;

    // workspace carve (16B aligned)
    char* w = (char*)d_ws;
    bf16_t* Plb  = (bf16_t*)w;  w += (size_t)M * HIDC * 2;
    bf16_t* Prb  = (bf16_t*)w;  w += (size_t)M * HIDC * 2;
    bf16_t* Hb   = (bf16_t*)w;  w += (size_t)M * HIDC * 2;
    bf16_t* Wb1  = (bf16_t*)w;  w += (size_t)256 * IN_DIMC * 2;
    bf16_t* Wb2  = (bf16_t*)w;  w += (size_t)256 * HIDC * 2;
    bf16_t* Wb3  = (bf16_t*)w;  w += (size_t)256 * HIDC * 2;
    int*   rowptr= (int*)w;     w += (size_t)(M + 16) * 4;
    int*   col   = (int*)w;     w += (size_t)N_EDGESC * 4;
    int*   cursor= (int*)w;     w += (size_t)M * 4;
    int*   degi  = (int*)w;     w += (size_t)M * 4;
    int*   slocal= (int*)w;     w += (size_t)M * 4;
    int*   spart = (int*)w;     w += 256 * 4;
    float* stats = (float*)w;   w += (size_t)3 * NREP * 256 * 4;   // zeroed in init

    float* stats1 = stats;
    float* stats2 = stats + NREP * 256;
    float* stats3 = stats + 2 * NREP * 256;

    const int nP128 = (M + 127) / 128;                  // 391
    const dim3 l1_grid(nP128);                          // fused 128x256 tile
    const dim3 hid_grid(((nP128 + 7) / 8) * 16);        // pair-colocation decode
    const int agg_blocks = (M + NB_AGG - 1) / NB_AGG;
    const int init_total = 2 * 128 * IN_DIMC + 4 * 128 * HIDC + 3 * NREP * 256 + M;

    // ---- init (weights + zeros, one dispatch) ----
    init_kernel<<<(init_total + 255) / 256, 256, 0, stream>>>(W1l, W1r, W2l, W2r, W3l, W3r,
                                                              Wb1, Wb2, Wb3, degi, stats);
    // ---- CSR build (4 dispatches) ----
    degi_kernel<<<(N_EDGESC + 255) / 256, 256, 0, stream>>>(ei, degi);
    scan1_kernel<<<SCAN_NB, 256, 0, stream>>>(degi, slocal, spart);
    scan3_kernel<<<SCAN_NB, 256, 0, stream>>>(slocal, spart, rowptr, cursor);
    fill_kernel<<<(N_EDGESC + 255) / 256, 256, 0, stream>>>(ei, cursor, col);

    // ---- layer 1 (K=768, fused 128x256 tile, R5 config) ----
    gemm_l1_kernel<<<l1_grid, 256, 0, stream>>>(x, Wb1, Plb, Prb, M);
    agg_combine_kernel<<<agg_blocks, 128, 0, stream>>>(rowptr, col, Plb, Prb, b1, Hb, stats1, M);

    // ---- layer 2 (K=128; BN1 finalize + BN1+ReLU fused into the GEMM) ----
    gemm_hid_kernel<<<hid_grid, 256, 0, stream>>>(Hb, Wb2, stats1, g1, be1, Plb, Prb, M);
    agg_combine_kernel<<<agg_blocks, 128, 0, stream>>>(rowptr, col, Plb, Prb, b2, Hb, stats2, M);

    // ---- layer 3 (K=128; BN2 finalize + BN2+ReLU fused) ----
    gemm_hid_kernel<<<hid_grid, 256, 0, stream>>>(Hb, Wb3, stats2, g2, be2, Plb, Prb, M);
    agg_combine_kernel<<<agg_blocks, 128, 0, stream>>>(rowptr, col, Plb, Prb, b3, Hb, stats3, M);

    // ---- BN3 finalize + pool + head (one dispatch) ----
    poolhead_kernel<<<N_GRAPHSC, 128, 0, stream>>>(Hb, stats3, g3, be3, batch, Wlin, blin,
                                                   (float*)d_out, M);
}